// Round 1
// baseline (663.813 us; speedup 1.0000x reference)
//
#include <hip/hip_runtime.h>
#include <hip/hip_bf16.h>
#include <math.h>

#define NB 32
#define NS 2048
#define ND 8
#define NH 256
#define NK 1792      // 7*NH
#define NO 256
#define NM (NB*NS)   // 65536
#define WSTEP 0.03125f

typedef __attribute__((ext_vector_type(8))) short short8;
typedef __attribute__((ext_vector_type(4))) float f32x4;

__device__ __forceinline__ float fast_sin(float x){
    float r = x * 0.15915494309189535f;   // to revolutions
    r = r - floorf(r);
    return __builtin_amdgcn_sinf(r);
}
__device__ __forceinline__ float fast_cos(float x){
    float r = x * 0.15915494309189535f;
    r = r - floorf(r);
    return __builtin_amdgcn_cosf(r);
}
__device__ __forceinline__ unsigned short bf16_rn(float f){
    union { float f; unsigned int u; } v; v.f = f;
    unsigned int u = v.u;
    unsigned int r = (u + 0x7FFFu + ((u >> 16) & 1u)) >> 16;
    return (unsigned short)r;
}
__device__ __forceinline__ float xform(int c, float v){
    switch(c){
        case 0: case 4: return fast_cos(v);
        case 1: case 5: return fast_sin(v);
        case 2:         return fast_cos(0.5f*v);
        case 3:         return fast_sin(0.5f*v);
        default:        return v;
    }
}

// ---------------- kernel 1: delta[t][b][h] = wrap(x[b,t,:] @ We[h,:] + be[h]) ----
extern "C" __global__ __launch_bounds__(256)
void k_delta(const float* __restrict__ x, const float* __restrict__ We,
             const float* __restrict__ be, float* __restrict__ delta){
    int tb = blockIdx.x;          // t*NB + b
    int h  = threadIdx.x;
    int t  = tb >> 5;
    int b  = tb & 31;
    const float* xr = x + ((size_t)b*NS + t)*ND;
    float4 xv0 = *(const float4*)xr;
    float4 xv1 = *(const float4*)(xr + 4);
    const float* wr = We + h*ND;
    float4 w0 = *(const float4*)wr;
    float4 w1 = *(const float4*)(wr + 4);
    float pt = be[h]
        + xv0.x*w0.x + xv0.y*w0.y + xv0.z*w0.z + xv0.w*w0.w
        + xv1.x*w1.x + xv1.y*w1.y + xv1.z*w1.z + xv1.w*w1.w;
    float s, c;
    sincosf(pt, &s, &c);                 // mirror reference atan2(sin,cos) exactly
    delta[(size_t)tb*NH + h] = atan2f(s, c);
}

// ---------------- kernel 2: sequential scan per (b,h) ---------------------------
extern "C" __global__ __launch_bounds__(256)
void k_scan(const float* __restrict__ x, const float* __restrict__ delta,
            float* __restrict__ ph_hist, float* __restrict__ wb_hist){
    __shared__ float rep[NS];
    int b = blockIdx.x, h = threadIdx.x;
    // recompute is_rep flags into LDS (t==0 -> 0)
    for(int tt = 0; tt < NS/256; ++tt){
        int t = tt*256 + h;
        float fl = 0.f;
        if(t > 0){
            const float* a = x + ((size_t)b*NS + t)*ND;
            bool eq = true;
            #pragma unroll
            for(int d = 0; d < ND; ++d) eq = eq && (a[d] == a[d-ND]);
            fl = eq ? 1.f : 0.f;
        }
        rep[t] = fl;
    }
    __syncthreads();

    const float* dp = delta + (size_t)b*NH + h;       // stride NB*NH per t
    float* pp = ph_hist + (size_t)b*NS*NH + h;
    float* wp = wb_hist + (size_t)b*NS*NH + h;
    float ph = 0.f, wb = 0.f;
    float dbuf[8];
    #pragma unroll
    for(int j = 0; j < 8; ++j) dbuf[j] = dp[(size_t)j*NB*NH];

    for(int tc = 0; tc < NS; tc += 8){
        float dn[8];
        if(tc + 8 < NS){
            #pragma unroll
            for(int j = 0; j < 8; ++j) dn[j] = dp[(size_t)(tc+8+j)*NB*NH];
        } else {
            #pragma unroll
            for(int j = 0; j < 8; ++j) dn[j] = 0.f;
        }
        #pragma unroll
        for(int j = 0; j < 8; ++j){
            int t = tc + j;
            float d   = dbuf[j];
            float wb2 = wb + WSTEP;
            float sw  = sinf(wb2);           // accurate: feeds fp32-compared output
            ph = ph + d - sw;                // COUPLING = -1
            float wbr = wb2 + d;
            wb = (rep[t] != 0.f) ? wbr : wb2;
            pp[(size_t)t*NH] = ph;
            wp[(size_t)t*NH] = wb;
        }
        #pragma unroll
        for(int j = 0; j < 8; ++j) dbuf[j] = dn[j];
    }
}

// ---------------- kernel 3: logits = readout(ph,wb) @ Wr.T + br  (bf16 MFMA) ----
extern "C" __global__ __launch_bounds__(512)
void k_logits(const float* __restrict__ ph_hist, const float* __restrict__ wb_hist,
              const float* __restrict__ Wr, const float* __restrict__ br,
              float* __restrict__ logits){
    // A-tile: 128 rows x 32 k (bf16), row stride padded to 40
    // B-tile: 256 cols x 32 k (bf16, k-major per output col), stride 40
    __shared__ __align__(16) unsigned short Al[128][40];
    __shared__ __align__(16) unsigned short Bl[256][40];
    int tid  = threadIdx.x;
    int m0   = blockIdx.x * 128;
    int lane = tid & 63, wid = tid >> 6;
    int wm = wid >> 2, wn = wid & 3;     // wave tile: 64x64

    f32x4 acc[4][4];
    f32x4 zz = {0.f, 0.f, 0.f, 0.f};
    #pragma unroll
    for(int i = 0; i < 4; ++i)
        #pragma unroll
        for(int j = 0; j < 4; ++j) acc[i][j] = zz;

    int arow = tid >> 2, ah = (tid & 3) * 8;   // A staging coords
    int bn   = tid >> 1, bk = (tid & 1) * 16;  // B staging coords

    for(int ks = 0; ks < NK/32; ++ks){
        int k0 = ks * 32;
        int c  = k0 >> 8;        // channel 0..6 (uniform per K-step)
        int hb = k0 & 255;

        { // stage A: compute readout channel -> bf16
            const float* src = (c == 4 || c == 5) ? wb_hist : ph_hist;
            const float* p = src + (size_t)(m0 + arow)*NH + hb + ah;
            float4 v0 = *(const float4*)p;
            float4 v1 = *(const float4*)(p + 4);
            float v[8] = {v0.x, v0.y, v0.z, v0.w, v1.x, v1.y, v1.z, v1.w};
            unsigned int pk[4];
            #pragma unroll
            for(int j = 0; j < 4; ++j){
                float a0 = xform(c, v[2*j]);
                float a1 = xform(c, v[2*j+1]);
                pk[j] = (unsigned int)bf16_rn(a0) | ((unsigned int)bf16_rn(a1) << 16);
            }
            *(uint4*)&Al[arow][ah] = make_uint4(pk[0], pk[1], pk[2], pk[3]);
        }
        { // stage B: Wr fp32 -> bf16, k-major rows per output col
            const float* q = Wr + (size_t)bn*NK + k0 + bk;
            float4 q0 = *(const float4*)q;
            float4 q1 = *(const float4*)(q + 4);
            float4 q2 = *(const float4*)(q + 8);
            float4 q3 = *(const float4*)(q + 12);
            float w[16] = {q0.x,q0.y,q0.z,q0.w, q1.x,q1.y,q1.z,q1.w,
                           q2.x,q2.y,q2.z,q2.w, q3.x,q3.y,q3.z,q3.w};
            unsigned int pk[8];
            #pragma unroll
            for(int j = 0; j < 8; ++j)
                pk[j] = (unsigned int)bf16_rn(w[2*j]) | ((unsigned int)bf16_rn(w[2*j+1]) << 16);
            *(uint4*)&Bl[bn][bk]     = make_uint4(pk[0], pk[1], pk[2], pk[3]);
            *(uint4*)&Bl[bn][bk + 8] = make_uint4(pk[4], pk[5], pk[6], pk[7]);
        }
        __syncthreads();

        int kg = lane >> 4, l15 = lane & 15;
        short8 afr[4], bfr[4];
        #pragma unroll
        for(int mf = 0; mf < 4; ++mf)
            afr[mf] = *(const short8*)&Al[wm*64 + mf*16 + l15][kg*8];
        #pragma unroll
        for(int nf = 0; nf < 4; ++nf)
            bfr[nf] = *(const short8*)&Bl[wn*64 + nf*16 + l15][kg*8];
        #pragma unroll
        for(int mf = 0; mf < 4; ++mf)
            #pragma unroll
            for(int nf = 0; nf < 4; ++nf)
                acc[mf][nf] = __builtin_amdgcn_mfma_f32_16x16x32_bf16(
                    afr[mf], bfr[nf], acc[mf][nf], 0, 0, 0);
        __syncthreads();
    }

    int l15 = lane & 15, lg = lane >> 4;
    #pragma unroll
    for(int nf = 0; nf < 4; ++nf){
        int col = wn*64 + nf*16 + l15;
        float bias = br[col];
        #pragma unroll
        for(int mf = 0; mf < 4; ++mf){
            int row = m0 + wm*64 + mf*16 + lg*4;
            #pragma unroll
            for(int r = 0; r < 4; ++r)
                logits[(size_t)(row + r)*NO + col] = acc[mf][nf][r] + bias;
        }
    }
}

// ---------------- launcher ------------------------------------------------------
extern "C" void kernel_launch(void* const* d_in, const int* in_sizes, int n_in,
                              void* d_out, int out_size, void* d_ws, size_t ws_size,
                              hipStream_t stream){
    const float* x  = (const float*)d_in[0];
    const float* We = (const float*)d_in[1];
    const float* be = (const float*)d_in[2];
    const float* Wr = (const float*)d_in[3];
    const float* br = (const float*)d_in[4];

    float* logits = (float*)d_out;
    float* ph     = logits + (size_t)NM*NO;
    float* wb     = ph + (size_t)NM*NH;
    float* delta  = logits;  // reuse logits region as delta scratch [t][b][h]

    hipLaunchKernelGGL(k_delta,  dim3(NS*NB), dim3(256), 0, stream, x, We, be, delta);
    hipLaunchKernelGGL(k_scan,   dim3(NB),    dim3(256), 0, stream, x, delta, ph, wb);
    hipLaunchKernelGGL(k_logits, dim3(NM/128), dim3(512), 0, stream, ph, wb, Wr, br, logits);
}

// Round 4
// 425.147 us; speedup vs baseline: 1.5614x; 1.5614x over previous
//
#include <hip/hip_runtime.h>
#include <hip/hip_bf16.h>
#include <math.h>

#define NB 32
#define NS 2048
#define ND 8
#define NH 256
#define NK 1792      // 7*NH
#define NO 256
#define NM (NB*NS)   // 65536
#define WSTEP 0.03125f
#define CCH 64            // chunks over time
#define LCH (NS/CCH)      // 32 steps per chunk

typedef __attribute__((ext_vector_type(8))) short short8;
typedef __attribute__((ext_vector_type(4))) float f32x4;

// inter-pass scratch (static device globals; fully rewritten every call)
__device__ float g_ssum[NB*CCH*NH];
__device__ float g_wb0 [NB*CCH*NH];
__device__ float g_esum[NB*CCH*NH];
__device__ float g_ph0 [NB*CCH*NH];
__device__ float g_rep [NB*NS];

__device__ __forceinline__ float fast_sin(float x){
    float r = x * 0.15915494309189535f;
    r = r - floorf(r);
    return __builtin_amdgcn_sinf(r);
}
__device__ __forceinline__ float fast_cos(float x){
    float r = x * 0.15915494309189535f;
    r = r - floorf(r);
    return __builtin_amdgcn_cosf(r);
}
__device__ __forceinline__ unsigned short bf16_rn(float f){
    union { float f; unsigned int u; } v; v.f = f;
    unsigned int u = v.u;
    unsigned int r = (u + 0x7FFFu + ((u >> 16) & 1u)) >> 16;
    return (unsigned short)r;
}
__device__ __forceinline__ float xform(int c, float v){
    switch(c){
        case 0: case 4: return fast_cos(v);
        case 1: case 5: return fast_sin(v);
        case 2:         return fast_cos(0.5f*v);
        case 3:         return fast_sin(0.5f*v);
        default:        return v;
    }
}

// ---- pass 1: delta[t][b][h], rep[b][t], chunk s-sums ---------------------------
extern "C" __global__ __launch_bounds__(256)
void k_delta(const float* __restrict__ x, const float* __restrict__ We,
             const float* __restrict__ be, float* __restrict__ delta){
    int blk = blockIdx.x;
    int b = blk >> 6;            // / CCH
    int c = blk & (CCH-1);
    int t0 = c * LCH;
    int h = threadIdx.x;
    __shared__ float xs[(LCH+1)*ND];   // x rows t0-1 .. t0+LCH-1
    __shared__ float rep[LCH];

    // load x rows (66 float4s)
    for(int i = h; i < (LCH+1)*ND/4; i += 256){
        int row  = i >> 1;
        int col4 = (i & 1) * 4;
        int t = t0 - 1 + row; if(t < 0) t = 0;
        *(float4*)&xs[row*ND + col4] = *(const float4*)&x[((size_t)b*NS + t)*ND + col4];
    }
    __syncthreads();
    if(h < LCH){
        int t = t0 + h;
        float fl = 0.f;
        if(t > 0){
            bool eq = true;
            #pragma unroll
            for(int d2 = 0; d2 < ND; ++d2) eq = eq && (xs[(h+1)*ND+d2] == xs[h*ND+d2]);
            fl = eq ? 1.f : 0.f;
        }
        rep[h] = fl;
        g_rep[b*NS + t] = fl;
    }
    __syncthreads();

    float4 w0 = *(const float4*)&We[h*ND];
    float4 w1 = *(const float4*)&We[h*ND + 4];
    float bh = be[h];
    float ssum = 0.f;
    for(int j = 0; j < LCH; ++j){
        const float* xr = &xs[(j+1)*ND];
        float pt = bh + xr[0]*w0.x + xr[1]*w0.y + xr[2]*w0.z + xr[3]*w0.w
                      + xr[4]*w1.x + xr[5]*w1.y + xr[6]*w1.z + xr[7]*w1.w;
        float s, cc;
        sincosf(pt, &s, &cc);
        float d = atan2f(s, cc);
        delta[((size_t)(t0+j)*NB + b)*NH + h] = d;
        ssum += WSTEP + rep[j]*d;
    }
    g_ssum[(b*CCH + c)*NH + h] = ssum;
}

// ---- pass 2/4: exclusive prefix over chunks per (b,h) --------------------------
extern "C" __global__ __launch_bounds__(256)
void k_prefix_s(){
    int g = blockIdx.x*256 + threadIdx.x;   // 8192
    int b = g >> 8, h = g & 255;
    float acc = 0.f;
    for(int c = 0; c < CCH; ++c){
        size_t idx = ((size_t)(b*CCH + c))*NH + h;
        g_wb0[idx] = acc;
        acc += g_ssum[idx];
    }
}
extern "C" __global__ __launch_bounds__(256)
void k_prefix_e(){
    int g = blockIdx.x*256 + threadIdx.x;
    int b = g >> 8, h = g & 255;
    float acc = 0.f;
    for(int c = 0; c < CCH; ++c){
        size_t idx = ((size_t)(b*CCH + c))*NH + h;
        g_ph0[idx] = acc;
        acc += g_esum[idx];
    }
}

// ---- pass 3: within-chunk scan, write wb_hist, emit chunk e-sums ---------------
extern "C" __global__ __launch_bounds__(256)
void k_escan(const float* __restrict__ delta, float* __restrict__ wb_hist){
    int blk = blockIdx.x;
    int b = blk >> 6, c = blk & (CCH-1), t0 = c*LCH, h = threadIdx.x;
    __shared__ float rep[LCH];
    if(h < LCH) rep[h] = g_rep[b*NS + t0 + h];
    __syncthreads();
    float wb = g_wb0[(b*CCH + c)*NH + h];
    const float* dp = delta + (size_t)t0*NB*NH + b*NH + h;
    float* wp = wb_hist + ((size_t)b*NS + t0)*NH + h;
    float d[LCH];
    #pragma unroll
    for(int j = 0; j < LCH; ++j) d[j] = dp[(size_t)j*(NB*NH)];
    float esum = 0.f;
    #pragma unroll
    for(int j = 0; j < LCH; ++j){
        float wb2 = wb + WSTEP;
        float e = d[j] - sinf(wb2);
        esum += e;
        wb = wb2 + rep[j]*d[j];
        wp[(size_t)j*NH] = wb;
    }
    g_esum[(b*CCH + c)*NH + h] = esum;
}

// ---- pass 5: recompute e (bitwise-identical), write ph_hist --------------------
extern "C" __global__ __launch_bounds__(256)
void k_phw(const float* __restrict__ delta, float* __restrict__ ph_hist){
    int blk = blockIdx.x;
    int b = blk >> 6, c = blk & (CCH-1), t0 = c*LCH, h = threadIdx.x;
    __shared__ float rep[LCH];
    if(h < LCH) rep[h] = g_rep[b*NS + t0 + h];
    __syncthreads();
    float wb = g_wb0[(b*CCH + c)*NH + h];
    float ph = g_ph0[(b*CCH + c)*NH + h];
    const float* dp = delta + (size_t)t0*NB*NH + b*NH + h;
    float* pp = ph_hist + ((size_t)b*NS + t0)*NH + h;
    float d[LCH];
    #pragma unroll
    for(int j = 0; j < LCH; ++j) d[j] = dp[(size_t)j*(NB*NH)];
    #pragma unroll
    for(int j = 0; j < LCH; ++j){
        float wb2 = wb + WSTEP;
        float e = d[j] - sinf(wb2);
        ph += e;
        wb = wb2 + rep[j]*d[j];
        pp[(size_t)j*NH] = ph;
    }
}

// ---- pass 6: logits = readout(ph,wb) @ Wr.T + br  (bf16 MFMA) ------------------
extern "C" __global__ __launch_bounds__(512)
void k_logits(const float* __restrict__ ph_hist, const float* __restrict__ wb_hist,
              const float* __restrict__ Wr, const float* __restrict__ br,
              float* __restrict__ logits){
    __shared__ __align__(16) unsigned short Al[128][40];
    __shared__ __align__(16) unsigned short Bl[256][40];
    int tid  = threadIdx.x;
    int m0   = blockIdx.x * 128;
    int lane = tid & 63, wid = tid >> 6;
    int wm = wid >> 2, wn = wid & 3;

    f32x4 acc[4][4];
    f32x4 zz = {0.f, 0.f, 0.f, 0.f};
    #pragma unroll
    for(int i = 0; i < 4; ++i)
        #pragma unroll
        for(int j = 0; j < 4; ++j) acc[i][j] = zz;

    int arow = tid >> 2, ah = (tid & 3) * 8;
    int bn   = tid >> 1, bk = (tid & 1) * 16;

    for(int ks = 0; ks < NK/32; ++ks){
        int k0 = ks * 32;
        int c  = k0 >> 8;
        int hb = k0 & 255;

        {
            const float* src = (c == 4 || c == 5) ? wb_hist : ph_hist;
            const float* p = src + (size_t)(m0 + arow)*NH + hb + ah;
            float4 v0 = *(const float4*)p;
            float4 v1 = *(const float4*)(p + 4);
            float v[8] = {v0.x, v0.y, v0.z, v0.w, v1.x, v1.y, v1.z, v1.w};
            unsigned int pk[4];
            #pragma unroll
            for(int j = 0; j < 4; ++j){
                float a0 = xform(c, v[2*j]);
                float a1 = xform(c, v[2*j+1]);
                pk[j] = (unsigned int)bf16_rn(a0) | ((unsigned int)bf16_rn(a1) << 16);
            }
            *(uint4*)&Al[arow][ah] = make_uint4(pk[0], pk[1], pk[2], pk[3]);
        }
        {
            const float* q = Wr + (size_t)bn*NK + k0 + bk;
            float4 q0 = *(const float4*)q;
            float4 q1 = *(const float4*)(q + 4);
            float4 q2 = *(const float4*)(q + 8);
            float4 q3 = *(const float4*)(q + 12);
            float w[16] = {q0.x,q0.y,q0.z,q0.w, q1.x,q1.y,q1.z,q1.w,
                           q2.x,q2.y,q2.z,q2.w, q3.x,q3.y,q3.z,q3.w};
            unsigned int pk[8];
            #pragma unroll
            for(int j = 0; j < 8; ++j)
                pk[j] = (unsigned int)bf16_rn(w[2*j]) | ((unsigned int)bf16_rn(w[2*j+1]) << 16);
            *(uint4*)&Bl[bn][bk]     = make_uint4(pk[0], pk[1], pk[2], pk[3]);
            *(uint4*)&Bl[bn][bk + 8] = make_uint4(pk[4], pk[5], pk[6], pk[7]);
        }
        __syncthreads();

        int kg = lane >> 4, l15 = lane & 15;
        short8 afr[4], bfr[4];
        #pragma unroll
        for(int mf = 0; mf < 4; ++mf)
            afr[mf] = *(const short8*)&Al[wm*64 + mf*16 + l15][kg*8];
        #pragma unroll
        for(int nf = 0; nf < 4; ++nf)
            bfr[nf] = *(const short8*)&Bl[wn*64 + nf*16 + l15][kg*8];
        #pragma unroll
        for(int mf = 0; mf < 4; ++mf)
            #pragma unroll
            for(int nf = 0; nf < 4; ++nf)
                acc[mf][nf] = __builtin_amdgcn_mfma_f32_16x16x32_bf16(
                    afr[mf], bfr[nf], acc[mf][nf], 0, 0, 0);
        __syncthreads();
    }

    int l15 = lane & 15, lg = lane >> 4;
    #pragma unroll
    for(int nf = 0; nf < 4; ++nf){
        int col = wn*64 + nf*16 + l15;
        float bias = br[col];
        #pragma unroll
        for(int mf = 0; mf < 4; ++mf){
            int row = m0 + wm*64 + mf*16 + lg*4;
            #pragma unroll
            for(int r = 0; r < 4; ++r)
                logits[(size_t)(row + r)*NO + col] = acc[mf][nf][r] + bias;
        }
    }
}

// ---- launcher ------------------------------------------------------------------
extern "C" void kernel_launch(void* const* d_in, const int* in_sizes, int n_in,
                              void* d_out, int out_size, void* d_ws, size_t ws_size,
                              hipStream_t stream){
    const float* x  = (const float*)d_in[0];
    const float* We = (const float*)d_in[1];
    const float* be = (const float*)d_in[2];
    const float* Wr = (const float*)d_in[3];
    const float* br = (const float*)d_in[4];

    float* logits = (float*)d_out;
    float* ph     = logits + (size_t)NM*NO;
    float* wb     = ph + (size_t)NM*NH;
    float* delta  = logits;   // reuse logits region as delta scratch [t][b][h]

    hipLaunchKernelGGL(k_delta,    dim3(NB*CCH), dim3(256), 0, stream, x, We, be, delta);
    hipLaunchKernelGGL(k_prefix_s, dim3(32),     dim3(256), 0, stream);
    hipLaunchKernelGGL(k_escan,    dim3(NB*CCH), dim3(256), 0, stream, delta, wb);
    hipLaunchKernelGGL(k_prefix_e, dim3(32),     dim3(256), 0, stream);
    hipLaunchKernelGGL(k_phw,      dim3(NB*CCH), dim3(256), 0, stream, delta, ph);
    hipLaunchKernelGGL(k_logits,   dim3(NM/128), dim3(512), 0, stream, ph, wb, Wr, br, logits);
}